// Round 8
// baseline (62.813 us; speedup 1.0000x reference)
//
#include <hip/hip_runtime.h>
#include <math.h>

// Net: 4 layers of out = 0.8*(x@W^T) + 0.2*max_i(W[o,i]*x[b,i]) + b
// B=1024, dims 256 -> 512 -> 512 -> 512 -> 1. All fp32.
//
// R8 = R7 (57us: fused net, coalesced W panels, packed fp32 + max3)
//  + 8-deep (2 kg-group) named-register W prefetch: load-to-use ~384 cyc
//    covers L2 latency (R7's 1-group depth = ~192 cyc < L2 ~200-450 cyc)
//  + shufflevector-based v2f extraction from v4f loads (no packing movs)
// All register indices compile-time; no runtime-indexed arrays (R6 lesson).

#define NT   512
#define ROWS 4

typedef float v2f __attribute__((ext_vector_type(2)));
typedef float v4f __attribute__((ext_vector_type(4)));

#define V2LO(v) __builtin_shufflevector((v), (v), 0, 1)
#define V2HI(v) __builtin_shufflevector((v), (v), 2, 3)

// ws layout in float4 units
#define WT1_OFF 0
#define WT2_OFF 33280    // 32768 + 512 pad
#define WT3_OFF 99328    // 33280 + 65536 + 512 pad

__global__ __launch_bounds__(256) void transpose_all(
    const float* __restrict__ W1, const float* __restrict__ W2,
    const float* __restrict__ W3, float4* __restrict__ ws)
{
    const int tid = blockIdx.x * 256 + threadIdx.x;   // 0 .. 163839
    const float* W;
    float4* WT;
    int o, k4, K;
    if (tid < 32768) {                    // W1: O=512, K=256, K4=64
        W = W1; WT = ws + WT1_OFF; K = 256;
        o = tid >> 6; k4 = tid & 63;
    } else if (tid < 98304) {             // W2: O=512, K=512, K4=128
        const int idx = tid - 32768;
        W = W2; WT = ws + WT2_OFF; K = 512;
        o = idx >> 7; k4 = idx & 127;
    } else {                              // W3: O=512, K=512, K4=128
        const int idx = tid - 98304;
        W = W3; WT = ws + WT3_OFF; K = 512;
        o = idx >> 7; k4 = idx & 127;
    }
    float4 v = *(const float4*)&W[(size_t)o * K + 4 * k4];
    WT[(size_t)k4 * 512 + o] = v;
}

// One kg-group (4 x k4 = 16 k-elems) of compute for 4 rows.
#define COMPUTE_KG(W0, W1, W2, W3, KB)                                      \
    {                                                                       \
        _Pragma("unroll")                                                   \
        for (int j = 0; j < 4; ++j) {                                       \
            const v4f w = (j == 0) ? (W0) : (j == 1) ? (W1)                 \
                        : (j == 2) ? (W2) : (W3);                           \
            const v2f wL = V2LO(w), wH = V2HI(w);                           \
            const int k = ((KB) + j) * 4;                                   \
            _Pragma("unroll")                                               \
            for (int r = 0; r < ROWS; ++r) {                                \
                const v4f h = *(const v4f*)&hin[r][k];                      \
                const v2f hL = V2LO(h), hH = V2HI(h);                       \
                v2f pL = wL * hL;                                           \
                v2f pH = wH * hH;                                           \
                sL[r] += pL;                                                \
                sH[r] += pH;                                                \
                mL[r] = fmaxf(fmaxf(mL[r], pL[0]), pL[1]);                  \
                mH[r] = fmaxf(fmaxf(mH[r], pH[0]), pH[1]);                  \
            }                                                               \
        }                                                                   \
    }

// Thread t owns output neuron o=t for ROWS batch rows.
// W from global coalesced panels; h wave-uniform LDS broadcasts.
__device__ __forceinline__ void layer_bcast(
    const float (*__restrict__ hin)[512],
    float (*__restrict__ hout)[512],
    const v4f* __restrict__ WT,    // [K4][512]
    const float* __restrict__ bias,
    int K4, int t)
{
    v2f sL[ROWS], sH[ROWS];
    float mL[ROWS], mH[ROWS];
    #pragma unroll
    for (int r = 0; r < ROWS; ++r) {
        sL[r] = (v2f)0.f; sH[r] = (v2f)0.f;
        mL[r] = -INFINITY; mH[r] = -INFINITY;
    }

    const v4f* wp = WT + t;

    // preload kg0 -> a*, kg1 -> b*   (K4 >= 8 always)
    v4f a0 = wp[0],    a1 = wp[512],  a2 = wp[1024], a3 = wp[1536];
    v4f b0 = wp[2048], b1 = wp[2560], b2 = wp[3072], b3 = wp[3584];

    for (int kg = 0; kg < K4; kg += 8) {
        // ---- phase A: prefetch kg+8, compute kg ----
        v4f ta0 = a0, ta1 = a1, ta2 = a2, ta3 = a3;
        if (kg + 8 < K4) {                      // uniform (scalar) branch
            const v4f* q = wp + (size_t)(kg + 8) * 512;
            ta0 = q[0]; ta1 = q[512]; ta2 = q[1024]; ta3 = q[1536];
        }
        COMPUTE_KG(a0, a1, a2, a3, kg);
        a0 = ta0; a1 = ta1; a2 = ta2; a3 = ta3;

        // ---- phase B: prefetch kg+12, compute kg+4 ----
        v4f tb0 = b0, tb1 = b1, tb2 = b2, tb3 = b3;
        if (kg + 12 < K4) {
            const v4f* q = wp + (size_t)(kg + 12) * 512;
            tb0 = q[0]; tb1 = q[512]; tb2 = q[1024]; tb3 = q[1536];
        }
        COMPUTE_KG(b0, b1, b2, b3, kg + 4);
        b0 = tb0; b1 = tb1; b2 = tb2; b3 = tb3;
    }

    const float bo = bias[t];
    #pragma unroll
    for (int r = 0; r < ROWS; ++r) {
        v2f sv = sL[r] + sH[r];
        float s = sv[0] + sv[1];
        float m = fmaxf(mL[r], mH[r]);
        hout[r][t] = fmaf(0.2f, m, fmaf(0.8f, s, bo));
    }
}

__global__ __launch_bounds__(NT) void net_fused(
    const float* __restrict__ x,
    const v4f* __restrict__ WT1, const float* __restrict__ b1,
    const v4f* __restrict__ WT2, const float* __restrict__ b2,
    const v4f* __restrict__ WT3, const float* __restrict__ b3,
    const float* __restrict__ W4, const float* __restrict__ b4,
    float* __restrict__ out)
{
    __shared__ __align__(16) float ha[ROWS][512];
    __shared__ __align__(16) float hb[ROWS][512];
    __shared__ float red_s[8][ROWS];
    __shared__ float red_m[8][ROWS];

    const int t = threadIdx.x;
    const int row0 = blockIdx.x * ROWS;

    // stage x rows (4 x 256) into ha: one float2 per thread
    {
        const int r = t >> 7;
        const int c = (t & 127) * 2;
        float2 v = *(const float2*)&x[(size_t)(row0 + r) * 256 + c];
        ha[r][c]     = v.x;
        ha[r][c + 1] = v.y;
    }
    __syncthreads();

    layer_bcast(ha, hb, WT1, b1, 64,  t);   // x  -> h1
    __syncthreads();
    layer_bcast(hb, ha, WT2, b2, 128, t);   // h1 -> h2
    __syncthreads();
    layer_bcast(ha, hb, WT3, b3, 128, t);   // h2 -> h3
    __syncthreads();

    // ---- layer 4: O=1 ----
    const float w4 = W4[t];
    float ps[ROWS], pm[ROWS];
    #pragma unroll
    for (int r = 0; r < ROWS; ++r) {
        float p = w4 * hb[r][t];
        ps[r] = p;
        pm[r] = p;
    }
    #pragma unroll
    for (int off = 32; off; off >>= 1) {
        #pragma unroll
        for (int r = 0; r < ROWS; ++r) {
            ps[r] += __shfl_xor(ps[r], off, 64);
            pm[r] = fmaxf(pm[r], __shfl_xor(pm[r], off, 64));
        }
    }
    const int lane = t & 63;
    const int wave = t >> 6;
    if (lane == 0) {
        #pragma unroll
        for (int r = 0; r < ROWS; ++r) {
            red_s[wave][r] = ps[r];
            red_m[wave][r] = pm[r];
        }
    }
    __syncthreads();

    if (t < ROWS) {
        float s = red_s[0][t];
        float m = red_m[0][t];
        #pragma unroll
        for (int w = 1; w < 8; ++w) {
            s += red_s[w][t];
            m = fmaxf(m, red_m[w][t]);
        }
        out[row0 + t] = fmaf(0.2f, m, fmaf(0.8f, s, b4[0]));
    }
}

extern "C" void kernel_launch(void* const* d_in, const int* in_sizes, int n_in,
                              void* d_out, int out_size, void* d_ws, size_t ws_size,
                              hipStream_t stream)
{
    const float* x  = (const float*)d_in[0];
    const float* W1 = (const float*)d_in[1];
    const float* b1 = (const float*)d_in[2];
    const float* W2 = (const float*)d_in[3];
    const float* b2 = (const float*)d_in[4];
    const float* W3 = (const float*)d_in[5];
    const float* b3 = (const float*)d_in[6];
    const float* W4 = (const float*)d_in[7];
    const float* b4 = (const float*)d_in[8];

    float4* ws4 = (float4*)d_ws;

    transpose_all<<<640, 256, 0, stream>>>(W1, W2, W3, ws4);

    net_fused<<<256, NT, 0, stream>>>(
        x,
        (const v4f*)(ws4 + WT1_OFF), b1,
        (const v4f*)(ws4 + WT2_OFF), b2,
        (const v4f*)(ws4 + WT3_OFF), b3,
        W4, b4,
        (float*)d_out);
}